// Round 11
// baseline (324.444 us; speedup 1.0000x reference)
//
#include <hip/hip_runtime.h>
#include <cstdint>
#include <cstddef>

// ---------------------------------------------------------------------------
// EncoderBlock: pre-norm transformer block, f32 I/O, bf16 MFMA internals.
//   prep(T(weights)+LN1) -> GEMM256(QKV, V written as key-permuted V^T in
//   epilogue) -> flash-attn(S^T, XCD-pinned) -> GEMM(Wo,+b_o+x -> x1 f32) ->
//   ln2init(LN2 -> h  AND  d_out = x1+b2) -> GEMM256(W1,+b,relu) ->
//   GEMM256(W2, split4, f32 ATOMIC-ADD into d_out)      [7 launches]
// Round-11: split-K reduce launch eliminated -- W2 slices accumulate via
// global_atomic_add_f32 (unsafeAtomicAdd; lane-distinct addresses, no
// contention, f32 partials MORE precise than old bf16 partials); d_out
// initialized with x1+b2 inside the LN2 kernel (which already reads x1).
// Big GEMMs: 256x256, BK=64, minimal-barrier schedule (2 barriers/K-tile,
// counted vmcnt(4)). Attention: round-10 config (ones-column denominator,
// within-tile QK/PV pipeline, XCD-pinned, epilogue-produced V^T).
// ---------------------------------------------------------------------------

typedef __attribute__((ext_vector_type(8))) __bf16 bf16x8;
typedef __attribute__((ext_vector_type(4))) __bf16 bf16x4;
typedef __attribute__((ext_vector_type(4))) float f32x4;

__device__ __forceinline__ void async16(const void* g, void* l) {
  __builtin_amdgcn_global_load_lds(
      (__attribute__((address_space(1))) void*)g,
      (__attribute__((address_space(3))) void*)l, 16, 0, 0);
}

__device__ __forceinline__ f32x4 mfma16(bf16x8 a, bf16x8 b, f32x4 c) {
  return __builtin_amdgcn_mfma_f32_16x16x32_bf16(a, b, c, 0, 0, 0);
}

template <int N>
__device__ __forceinline__ void wait_vmcnt() {
  if constexpr (N == 0) {
    asm volatile("s_waitcnt vmcnt(0)" ::: "memory");
  } else if constexpr (N == 3) {
    asm volatile("s_waitcnt vmcnt(3)" ::: "memory");
  } else {
    asm volatile("s_waitcnt vmcnt(4)" ::: "memory");
  }
}
__device__ __forceinline__ void barrier_raw() {
  asm volatile("s_barrier" ::: "memory");
}

// ---------------------------------------------------------------------------
// LayerNorm body (1 wave per token, D=1024).
// ---------------------------------------------------------------------------
__device__ __forceinline__ void ln_body(const float* __restrict__ xin,
                                        const float* __restrict__ g,
                                        const float* __restrict__ bt,
                                        __bf16* __restrict__ out, int tok,
                                        int lane) {
  const int base0 = lane * 8, base1 = 512 + lane * 8;
  const float* xr = xin + (size_t)tok * 1024;
  float v[16];
  float4 a0 = *(const float4*)(xr + base0);
  float4 a1 = *(const float4*)(xr + base0 + 4);
  float4 a2 = *(const float4*)(xr + base1);
  float4 a3 = *(const float4*)(xr + base1 + 4);
  v[0] = a0.x; v[1] = a0.y; v[2] = a0.z; v[3] = a0.w;
  v[4] = a1.x; v[5] = a1.y; v[6] = a1.z; v[7] = a1.w;
  v[8] = a2.x; v[9] = a2.y; v[10] = a2.z; v[11] = a2.w;
  v[12] = a3.x; v[13] = a3.y; v[14] = a3.z; v[15] = a3.w;
  float s = 0.f, s2 = 0.f;
#pragma unroll
  for (int i = 0; i < 16; i++) { s += v[i]; s2 += v[i] * v[i]; }
#pragma unroll
  for (int m = 1; m < 64; m <<= 1) {
    s += __shfl_xor(s, m);
    s2 += __shfl_xor(s2, m);
  }
  const float mean = s * (1.f / 1024.f);
  const float var = s2 * (1.f / 1024.f) - mean * mean;
  const float rstd = rsqrtf(var + 1e-6f);
  float4 g0 = *(const float4*)(g + base0), g1 = *(const float4*)(g + base0 + 4);
  float4 g2 = *(const float4*)(g + base1), g3 = *(const float4*)(g + base1 + 4);
  float4 b0 = *(const float4*)(bt + base0), b1v = *(const float4*)(bt + base0 + 4);
  float4 b2v = *(const float4*)(bt + base1), b3 = *(const float4*)(bt + base1 + 4);
  float gg[16] = {g0.x, g0.y, g0.z, g0.w, g1.x, g1.y, g1.z, g1.w,
                  g2.x, g2.y, g2.z, g2.w, g3.x, g3.y, g3.z, g3.w};
  float bb[16] = {b0.x, b0.y, b0.z, b0.w, b1v.x, b1v.y, b1v.z, b1v.w,
                  b2v.x, b2v.y, b2v.z, b2v.w, b3.x, b3.y, b3.z, b3.w};
  bf16x8 o0, o1;
#pragma unroll
  for (int j = 0; j < 8; j++) {
    o0[j] = (__bf16)((v[j] - mean) * rstd * gg[j] + bb[j]);
    o1[j] = (__bf16)((v[8 + j] - mean) * rstd * gg[8 + j] + bb[8 + j]);
  }
  __bf16* op = out + (size_t)tok * 1024;
  *(bf16x8*)(op + base0) = o0;
  *(bf16x8*)(op + base1) = o1;
}

// ---------------------------------------------------------------------------
// prep: ALL weight transposes (f32 -> bf16) + LN1, fused into one launch.
// ---------------------------------------------------------------------------
__global__ __launch_bounds__(256) void prep_kernel(
    const float* __restrict__ Wq, const float* __restrict__ Wk,
    const float* __restrict__ Wv, const float* __restrict__ Wo,
    const float* __restrict__ W1, const float* __restrict__ W2,
    const float* __restrict__ x, const float* __restrict__ ln1g,
    const float* __restrict__ ln1b, __bf16* __restrict__ WqkvT,
    __bf16* __restrict__ WoT, __bf16* __restrict__ W1T,
    __bf16* __restrict__ W2T, __bf16* __restrict__ h) {
  const int id = blockIdx.x;
  if (id >= 3072) {
    const int tok = (id - 3072) * 4 + (threadIdx.x >> 6);
    ln_body(x, ln1g, ln1b, h, tok, threadIdx.x & 63);
    return;
  }
  const float* in;
  __bf16* out;
  int ld_in, ld_out, c0, r0;
  if (id < 1024) {
    const int which = id >> 8, tl = id & 255;
    c0 = (tl & 15) * 64;
    r0 = (tl >> 4) * 64;
    ld_in = 1024;
    ld_out = 1024;
    if (which == 0) { in = Wq; out = WqkvT; }
    else if (which == 1) { in = Wk; out = WqkvT + 1048576; }
    else if (which == 2) { in = Wv; out = WqkvT + 2097152; }
    else { in = Wo; out = WoT; }
  } else if (id < 2048) {
    const int tl = id - 1024;
    c0 = (tl & 63) * 64;
    r0 = (tl >> 6) * 64;
    in = W1; out = W1T; ld_in = 4096; ld_out = 1024;
  } else {
    const int tl = id - 2048;
    c0 = (tl & 15) * 64;
    r0 = (tl >> 4) * 64;
    in = W2; out = W2T; ld_in = 1024; ld_out = 4096;
  }
  __shared__ __bf16 tile[64][65];
  const int tx = threadIdx.x & 63, ty = threadIdx.x >> 6;
#pragma unroll
  for (int i = 0; i < 16; i++) {
    int r = ty + i * 4;
    tile[r][tx] = (__bf16)in[(size_t)(r0 + r) * ld_in + c0 + tx];
  }
  __syncthreads();
#pragma unroll
  for (int i = 0; i < 16; i++) {
    int r = ty + i * 4;
    out[(size_t)(c0 + r) * ld_out + r0 + tx] = tile[tx][r];
  }
}

// ---------------------------------------------------------------------------
// ln2init: LN2 (x1 -> h bf16)  AND  d_out init = x1 + b2 (f32).
// ---------------------------------------------------------------------------
__global__ __launch_bounds__(256) void ln2init_kernel(
    const float* __restrict__ xin, const float* __restrict__ g,
    const float* __restrict__ bt, const float* __restrict__ b2,
    __bf16* __restrict__ out, float* __restrict__ dout) {
  const int tok = blockIdx.x * 4 + (threadIdx.x >> 6);
  const int lane = threadIdx.x & 63;
  const int base0 = lane * 8, base1 = 512 + lane * 8;
  const float* xr = xin + (size_t)tok * 1024;
  float v[16];
  float4 a0 = *(const float4*)(xr + base0);
  float4 a1 = *(const float4*)(xr + base0 + 4);
  float4 a2 = *(const float4*)(xr + base1);
  float4 a3 = *(const float4*)(xr + base1 + 4);
  v[0] = a0.x; v[1] = a0.y; v[2] = a0.z; v[3] = a0.w;
  v[4] = a1.x; v[5] = a1.y; v[6] = a1.z; v[7] = a1.w;
  v[8] = a2.x; v[9] = a2.y; v[10] = a2.z; v[11] = a2.w;
  v[12] = a3.x; v[13] = a3.y; v[14] = a3.z; v[15] = a3.w;
  float s = 0.f, s2 = 0.f;
#pragma unroll
  for (int i = 0; i < 16; i++) { s += v[i]; s2 += v[i] * v[i]; }
#pragma unroll
  for (int m = 1; m < 64; m <<= 1) {
    s += __shfl_xor(s, m);
    s2 += __shfl_xor(s2, m);
  }
  const float mean = s * (1.f / 1024.f);
  const float var = s2 * (1.f / 1024.f) - mean * mean;
  const float rstd = rsqrtf(var + 1e-6f);
  float4 g0 = *(const float4*)(g + base0), g1 = *(const float4*)(g + base0 + 4);
  float4 g2 = *(const float4*)(g + base1), g3 = *(const float4*)(g + base1 + 4);
  float4 b0 = *(const float4*)(bt + base0), b1v = *(const float4*)(bt + base0 + 4);
  float4 b2v = *(const float4*)(bt + base1), b3 = *(const float4*)(bt + base1 + 4);
  float gg[16] = {g0.x, g0.y, g0.z, g0.w, g1.x, g1.y, g1.z, g1.w,
                  g2.x, g2.y, g2.z, g2.w, g3.x, g3.y, g3.z, g3.w};
  float bb[16] = {b0.x, b0.y, b0.z, b0.w, b1v.x, b1v.y, b1v.z, b1v.w,
                  b2v.x, b2v.y, b2v.z, b2v.w, b3.x, b3.y, b3.z, b3.w};
  bf16x8 o0, o1;
#pragma unroll
  for (int j = 0; j < 8; j++) {
    o0[j] = (__bf16)((v[j] - mean) * rstd * gg[j] + bb[j]);
    o1[j] = (__bf16)((v[8 + j] - mean) * rstd * gg[8 + j] + bb[8 + j]);
  }
  __bf16* op = out + (size_t)tok * 1024;
  *(bf16x8*)(op + base0) = o0;
  *(bf16x8*)(op + base1) = o1;
  // d_out init = x1 + b2 (W2 slices atomically add on top)
  float4 c0v = *(const float4*)(b2 + base0), c1 = *(const float4*)(b2 + base0 + 4);
  float4 c2 = *(const float4*)(b2 + base1), c3 = *(const float4*)(b2 + base1 + 4);
  float* dp = dout + (size_t)tok * 1024;
  float4 d0 = {v[0] + c0v.x, v[1] + c0v.y, v[2] + c0v.z, v[3] + c0v.w};
  float4 d1 = {v[4] + c1.x, v[5] + c1.y, v[6] + c1.z, v[7] + c1.w};
  float4 d2 = {v[8] + c2.x, v[9] + c2.y, v[10] + c2.z, v[11] + c2.w};
  float4 d3 = {v[12] + c3.x, v[13] + c3.y, v[14] + c3.z, v[15] + c3.w};
  *(float4*)(dp + base0) = d0;
  *(float4*)(dp + base0 + 4) = d1;
  *(float4*)(dp + base1) = d2;
  *(float4*)(dp + base1 + 4) = d3;
}

// ---------------------------------------------------------------------------
// gemm256: C[M,N] = A[M,K](bf16) * BT[N,K](bf16)^T. 256x256 tile, BK=64,
// 512 thr = 2x4 waves. Minimal-barrier K-loop (2 barriers/K-tile), counted
// vmcnt(4). setprio around MFMA clusters; chunk-XOR LDS swizzle.
// EPI: 0 -> bf16; 2 -> +bias(f32), relu -> bf16;
//      3 -> QKV: V tiles (n0>=2048) write key-permuted V^T directly;
//      4 -> split-K slice accumulates into f32 C via global atomic add
//           (C pre-initialized with residual+bias by ln2init).
// ---------------------------------------------------------------------------
template <int EPI, int SPLITS = 1>
__global__ __launch_bounds__(512, 2) void gemm256(
    const __bf16* __restrict__ A, int lda, const __bf16* __restrict__ BT,
    int ldb, void* __restrict__ C, int ldc, int Kb,
    const float* __restrict__ bias, __bf16* __restrict__ VTout) {
  const int t = threadIdx.x;
  const int m0 = blockIdx.x * 256, n0 = blockIdx.y * 256;
  const int kz = (SPLITS > 1) ? blockIdx.z : 0;
  __shared__ __align__(16) __bf16 As[2][2][8192];
  __shared__ __align__(16) __bf16 Bs[2][2][8192];
  const int lane = t & 63;
  const int quad = lane >> 4, l15 = lane & 15;
  const int w = t >> 6, wm = w >> 2, wn = w & 3;

  f32x4 acc[8][4] = {};

  const int rr = t >> 3;
  const int ca = (t & 7) ^ (rr & 7);
  const int cc = rr & 31;
  const int wnb = t >> 8;
  const int cb = (t & 7) ^ (cc & 7);
  const __bf16* gA = A + (size_t)kz * Kb + (size_t)(m0 + rr) * lda + ca * 8;
  const __bf16* gB = BT + (size_t)kz * Kb +
                     (size_t)(n0 + wnb * 64 + cc) * ldb + cb * 8;
  const size_t a64 = (size_t)64 * lda, a128 = (size_t)128 * lda;
  const size_t b32 = (size_t)32 * ldb, b128 = (size_t)128 * ldb;

  auto stageA = [&](int buf, int mq, int ko) {
    const __bf16* g = gA + (mq ? a64 : 0) + ko;
    __bf16* l = &As[buf][mq][t * 8];
    async16(g, l);
    async16(g + a128, l + 4096);
  };
  auto stageB = [&](int buf, int nq, int ko) {
    const __bf16* g = gB + (nq ? b32 : 0) + ko;
    __bf16* l = &Bs[buf][nq][t * 8];
    async16(g, l);
    async16(g + b128, l + 4096);
  };

  const int arow = wm * 4096 + l15 * 64;
  const int brow = wn * 2048 + l15 * 64;
  const int x7 = l15 & 7;

  auto loadA = [&](int buf, int mq, bf16x8 (&af)[4][2]) {
#pragma unroll
    for (int mi = 0; mi < 4; mi++)
#pragma unroll
      for (int kk = 0; kk < 2; kk++)
        af[mi][kk] = *(const bf16x8*)&As[buf][mq]
            [arow + mi * 1024 + (((kk * 4 + quad) ^ x7) * 8)];
  };
  auto loadB = [&](int buf, int nq, bf16x8 (&bv)[2][2]) {
#pragma unroll
    for (int ni = 0; ni < 2; ni++)
#pragma unroll
      for (int kk = 0; kk < 2; kk++)
        bv[ni][kk] = *(const bf16x8*)&Bs[buf][nq]
            [brow + ni * 1024 + (((kk * 4 + quad) ^ x7) * 8)];
  };
  auto mm = [&](int mq, int nq, const bf16x8 (&af)[4][2],
                const bf16x8 (&bv)[2][2]) {
    __builtin_amdgcn_s_setprio(1);
#pragma unroll
    for (int mi = 0; mi < 4; mi++)
#pragma unroll
      for (int ni = 0; ni < 2; ni++)
#pragma unroll
        for (int kk = 0; kk < 2; kk++)
          acc[mq * 4 + mi][nq * 2 + ni] =
              mfma16(af[mi][kk], bv[ni][kk], acc[mq * 4 + mi][nq * 2 + ni]);
    __builtin_amdgcn_s_setprio(0);
  };

  const int NT = Kb / 64;
  stageA(0, 0, 0); stageB(0, 0, 0); stageA(0, 1, 0); stageB(0, 1, 0);
  stageA(1, 0, 64); stageB(1, 0, 64);
  wait_vmcnt<4>();
  barrier_raw();

  bf16x8 af[4][2], b0[2][2], b1[2][2];
  for (int s = 0; s < NT; ++s) {
    const int buf = s & 1;
    const int ko1 = (s + 1) * 64, ko2 = (s + 2) * 64;
    loadA(buf, 0, af);
    loadB(buf, 0, b0);
    loadB(buf, 1, b1);
    if (s + 1 < NT) {
      stageA(buf ^ 1, 1, ko1);
      stageB(buf ^ 1, 1, ko1);
    }
    mm(0, 0, af, b0);
    mm(0, 1, af, b1);
    barrier_raw();  // all waves' A0/B0/B1 reads done before ko2 overwrites
    loadA(buf, 1, af);
    if (s + 2 < NT) {
      stageA(buf, 0, ko2);
      stageB(buf, 0, ko2);
      wait_vmcnt<4>();  // drains ko1 (tile s+1 A1,B1) + older; leaves ko2
    } else {
      wait_vmcnt<0>();
    }
    mm(1, 0, af, b0);
    mm(1, 1, af, b1);
    barrier_raw();  // A1/B1 reads done before next iter's ko1 overwrites
  }

  if constexpr (EPI == 3) {
    if (n0 >= 2048) {
      // V tile -> key-permuted V^T (feature-major, token permuted within 32)
      const int colb = m0 + wm * 128;
#pragma unroll
      for (int mi = 0; mi < 8; mi++) {
        const int tcol = colb + (mi >> 1) * 32 + quad * 8 + (mi & 1) * 4;
#pragma unroll
        for (int ni = 0; ni < 4; ni++) {
          const int vrow = n0 - 2048 + wn * 64 + ni * 16 + l15;
          bf16x4 o;
#pragma unroll
          for (int r = 0; r < 4; r++) o[r] = (__bf16)acc[mi][ni][r];
          *(bf16x4*)&VTout[(size_t)vrow * 4096 + tcol] = o;
        }
      }
      return;
    }
  }

  if constexpr (EPI == 4) {
    float* Cf = (float*)C;
#pragma unroll
    for (int mi = 0; mi < 8; mi++)
#pragma unroll
      for (int ni = 0; ni < 4; ni++)
#pragma unroll
        for (int r = 0; r < 4; r++) {
          const int row = m0 + wm * 128 + mi * 16 + quad * 4 + r;
          const int col = n0 + wn * 64 + ni * 16 + l15;
          unsafeAtomicAdd(&Cf[(size_t)row * ldc + col], acc[mi][ni][r]);
        }
    return;
  }

  float biasv[4];
  if constexpr (EPI == 2) {
#pragma unroll
    for (int ni = 0; ni < 4; ni++)
      biasv[ni] = bias[n0 + wn * 64 + ni * 16 + l15];
  }
  __bf16* Cb = (__bf16*)C;
#pragma unroll
  for (int mi = 0; mi < 8; mi++)
#pragma unroll
    for (int ni = 0; ni < 4; ni++)
#pragma unroll
      for (int r = 0; r < 4; r++) {
        const int row = m0 + wm * 128 + mi * 16 + quad * 4 + r;
        const int col = n0 + wn * 64 + ni * 16 + l15;
        float v = acc[mi][ni][r];
        if constexpr (EPI == 0 || EPI == 3) {
          Cb[(size_t)row * ldc + col] = (__bf16)v;
        } else {
          v += biasv[ni];
          Cb[(size_t)row * ldc + col] = (__bf16)fmaxf(v, 0.f);
        }
      }
}

// ---------------------------------------------------------------------------
// Older 128-wide GEMM (kept for Wo). EPI == 1: +bias(f32)+res(f32) -> f32.
// ---------------------------------------------------------------------------
template <int EPI, int TM, int SPLITS = 1>
__global__ __launch_bounds__(256) void gemm_bt(
    const __bf16* __restrict__ A, int lda, const __bf16* __restrict__ BT,
    int ldb, void* __restrict__ C, int ldc, int Kb,
    const float* __restrict__ bias, const float* __restrict__ res, int ldres) {
  const int t = threadIdx.x;
  const int m0 = blockIdx.x * TM, n0 = blockIdx.y * 128;
  const int kz = (SPLITS > 1) ? blockIdx.z : 0;
  __shared__ __align__(16) __bf16 As[3][TM * 32];
  __shared__ __align__(16) __bf16 Bs[3][128 * 32];
  const int lane = t & 63, w = t >> 6;
  const int quad = lane >> 4, l15 = lane & 15;
  const int wm = w >> 1, wn = w & 1;
  constexpr int MF = TM / 32;
  constexpr int LOADS = TM / 64 + 2;

  f32x4 acc[MF][4] = {};

  const int swc = ((t & 3) ^ ((t >> 3) & 3)) * 8;
  const __bf16* ga = A + (size_t)(m0 + (t >> 2)) * lda + swc + (size_t)kz * Kb;
  const __bf16* gb = BT + (size_t)(n0 + (t >> 2)) * ldb + swc + (size_t)kz * Kb;
  const size_t a64 = (size_t)64 * lda, b64 = (size_t)64 * ldb;

  auto stage = [&](int buf) {
#pragma unroll
    for (int i = 0; i < TM / 64; i++)
      async16(ga + i * a64, As[buf] + t * 8 + i * 2048);
    async16(gb, Bs[buf] + t * 8);
    async16(gb + b64, Bs[buf] + t * 8 + 2048);
    ga += 32;
    gb += 32;
  };
  const int ce = (quad ^ ((l15 >> 1) & 3)) * 8;
  auto compute = [&](int buf) {
    bf16x8 af[MF], bfr[4];
#pragma unroll
    for (int i = 0; i < MF; i++)
      af[i] = *(const bf16x8*)&As[buf][(wm * (TM / 2) + i * 16 + l15) * 32 + ce];
#pragma unroll
    for (int i = 0; i < 4; i++)
      bfr[i] = *(const bf16x8*)&Bs[buf][(wn * 64 + i * 16 + l15) * 32 + ce];
#pragma unroll
    for (int mi = 0; mi < MF; mi++)
#pragma unroll
      for (int ni = 0; ni < 4; ni++)
        acc[mi][ni] = mfma16(af[mi], bfr[ni], acc[mi][ni]);
  };

  const int iters = Kb / 32;
  stage(0);
  stage(1);
  int cur = 0, stg = 2;
  for (int it = 0; it < iters - 1; ++it) {
    wait_vmcnt<LOADS>();
    barrier_raw();
    if (it + 2 < iters) stage(stg);
    compute(cur);
    cur = (cur == 2) ? 0 : cur + 1;
    stg = (stg == 2) ? 0 : stg + 1;
  }
  wait_vmcnt<0>();
  barrier_raw();
  compute(cur);

  float biasv[4];
  if constexpr (EPI != 0) {
#pragma unroll
    for (int ni = 0; ni < 4; ni++)
      biasv[ni] = bias[n0 + wn * 64 + ni * 16 + l15];
  }
  __bf16* Cb = (__bf16*)C;
  if constexpr (SPLITS > 1)
    Cb += (size_t)kz * gridDim.x * TM * ldc;
#pragma unroll
  for (int mi = 0; mi < MF; mi++)
#pragma unroll
    for (int ni = 0; ni < 4; ni++)
#pragma unroll
      for (int r = 0; r < 4; r++) {
        const int row = m0 + wm * (TM / 2) + mi * 16 + quad * 4 + r;
        const int col = n0 + wn * 64 + ni * 16 + l15;
        float v = acc[mi][ni][r];
        if constexpr (EPI == 0) {
          Cb[(size_t)row * ldc + col] = (__bf16)v;
        } else if constexpr (EPI == 1) {
          v += biasv[ni] + res[(size_t)row * ldres + col];
          ((float*)C)[(size_t)row * ldc + col] = v;
        } else {
          v += biasv[ni];
          ((__bf16*)C)[(size_t)row * ldc + col] = (__bf16)fmaxf(v, 0.f);
        }
      }
}

// ---------------------------------------------------------------------------
// Flash attention via S^T (round-10 config). QBLK=128 (4 waves x 32 q as 2
// q-groups), KVBLK=128, XCD-pinned grid 512; K LDS 2x16KB; V^T LDS 2x16KB
// [64][128]; quad-grouped key-permuted V^T from the QKV-gemm epilogue;
// ones-column MFMA denominator; within-tile QK(kb+1) || exp(kb)+PV(kb).
// ---------------------------------------------------------------------------
__global__ __launch_bounds__(256, 2) void attn_kernel(
    const __bf16* __restrict__ QKV, const __bf16* __restrict__ VT,
    __bf16* __restrict__ ctx) {
  const int id = blockIdx.x;
  const int xg = id & 7, idx = id >> 3;  // 512 blocks
  const int bh = xg * 4 + (idx & 3);     // head-group pinned to XCD
  const int qt = idx >> 2;               // 0..15
  const int b = bh >> 4, h = bh & 15;
  const int t = threadIdx.x, w = t >> 6, lane = t & 63;
  const int quad = lane >> 4, l15 = lane & 15;
  const int tok0 = b * 2048;
  const int q0w = tok0 + qt * 128 + w * 32;

  __shared__ __align__(16) __bf16 Ks[2][128 * 64];   // [key][d]
  __shared__ __align__(16) __bf16 VTs[2][64 * 128];  // [d][key-perm]

  const float qs = 0.18033688011112042f;  // log2(e)/8 -> exp2-domain softmax
  bf16x8 qf[2][2];
#pragma unroll
  for (int mi = 0; mi < 2; mi++)
#pragma unroll
    for (int kb = 0; kb < 2; kb++) {
      const __bf16* src = QKV + (size_t)(q0w + mi * 16 + l15) * 3072 + h * 64 +
                          kb * 32 + quad * 8;
      bf16x8 r = *(const bf16x8*)src;
#pragma unroll
      for (int j = 0; j < 8; j++) r[j] = (__bf16)((float)r[j] * qs);
      qf[mi][kb] = r;
    }

  bf16x8 onesv;
#pragma unroll
  for (int j = 0; j < 8; j++) onesv[j] = (__bf16)1.0f;

  f32x4 O[2][4] = {};
  f32x4 Ol[2] = {};  // ones-column accumulation: softmax denominator per q-row

  const int krow = t >> 3;                       // 0..31 (K staging)
  const int kcg = (((t & 7) ^ (krow & 7)) * 8);  // K source chunk
  const int vrow = t >> 4;                       // 0..15 (V staging)
  const int vcg = (((t & 15) ^ (vrow & 7)) * 8); // V source chunk (16/row)
  const int x7 = l15 & 7;

  auto stage = [&](int buf, int kt) {
    const int ktok = tok0 + kt * 128;
#pragma unroll
    for (int j = 0; j < 4; j++) {
      const __bf16* gp =
          QKV + (size_t)(ktok + krow + j * 32) * 3072 + 1024 + h * 64 + kcg;
      async16(gp, Ks[buf] + t * 8 + j * 2048);
    }
#pragma unroll
    for (int j = 0; j < 4; j++) {
      const __bf16* gp =
          VT + (size_t)(h * 64 + vrow + j * 16) * 4096 + ktok + vcg;
      async16(gp, VTs[buf] + t * 8 + j * 2048);
    }
  };

  stage(0, 0);
  wait_vmcnt<0>();
  barrier_raw();

  int buf = 0;
  for (int kt = 0; kt < 16; ++kt) {
    if (kt + 1 < 16) stage(buf ^ 1, kt + 1);  // prefetch next K/V tile

    f32x4 sT[2][8];
    auto qkblk = [&](int kb) {
      __builtin_amdgcn_s_setprio(1);
#pragma unroll
      for (int kt8 = 2 * kb; kt8 < 2 * kb + 2; kt8++) {
        f32x4 a0 = {}, a1 = {};
#pragma unroll
        for (int kq = 0; kq < 2; kq++) {
          bf16x8 kf = *(const bf16x8*)&Ks[buf][(kt8 * 16 + l15) * 64 +
                                              (((kq * 4 + quad) ^ x7) * 8)];
          a0 = mfma16(kf, qf[0][kq], a0);
          a1 = mfma16(kf, qf[1][kq], a1);
        }
        sT[0][kt8] = a0;
        sT[1][kt8] = a1;
      }
      __builtin_amdgcn_s_setprio(0);
    };

    qkblk(0);
#pragma unroll
    for (int kb = 0; kb < 4; kb++) {
      if (kb < 3) qkblk(kb + 1);
      bf16x8 pf0, pf1;
#pragma unroll
      for (int hf = 0; hf < 2; hf++)
#pragma unroll
        for (int r = 0; r < 4; r++) {
          const float p0 = __builtin_amdgcn_exp2f(sT[0][2 * kb + hf][r]);
          const float p1 = __builtin_amdgcn_exp2f(sT[1][2 * kb + hf][r]);
          pf0[hf * 4 + r] = (__bf16)p0;
          pf1[hf * 4 + r] = (__bf16)p1;
        }
      __builtin_amdgcn_s_setprio(1);
#pragma unroll
      for (int nd = 0; nd < 4; nd++) {
        bf16x8 vf = *(const bf16x8*)&VTs[buf][(nd * 16 + l15) * 128 +
                                             (((4 * kb + quad) ^ x7) * 8)];
        O[0][nd] = mfma16(pf0, vf, O[0][nd]);
        O[1][nd] = mfma16(pf1, vf, O[1][nd]);
      }
      Ol[0] = mfma16(pf0, onesv, Ol[0]);
      Ol[1] = mfma16(pf1, onesv, Ol[1]);
      __builtin_amdgcn_s_setprio(0);
    }

    wait_vmcnt<0>();  // drain prefetch (issued before compute; L2-hit ~free)
    barrier_raw();    // all waves done reading buf; buf^1 fully staged
    buf ^= 1;
  }

  // epilogue: normalize by Ol (same row mapping as O), store (per q-group)
#pragma unroll
  for (int mi = 0; mi < 2; mi++) {
    float rl[4];
#pragma unroll
    for (int r = 0; r < 4; r++) rl[r] = 1.0f / Ol[mi][r];
#pragma unroll
    for (int nd = 0; nd < 4; nd++)
#pragma unroll
      for (int r = 0; r < 4; r++) {
        const int tokq = q0w + mi * 16 + quad * 4 + r;
        const int col = h * 64 + nd * 16 + l15;
        ctx[(size_t)tokq * 1024 + col] = (__bf16)(O[mi][nd][r] * rl[r]);
      }
  }
}

// ---------------------------------------------------------------------------
// Workspace layout (84 MB used), lifetime-packed:
//   [ 0, 8)  h      [ 8,16) W1T   [16,22) WqkvT   [22,24) WoT
//   [24,48)  QKV    [48,56) VT    [56,64) ctx
//   [32,64)  f1 (after attn: QKV tail/VT/ctx dead)
//   [64,80)  x1 (f32)             [80,88) W2T
// Pw2 partials no longer exist (atomic split-K into d_out).
// ---------------------------------------------------------------------------
extern "C" void kernel_launch(void* const* d_in, const int* in_sizes, int n_in,
                              void* d_out, int out_size, void* d_ws,
                              size_t ws_size, hipStream_t stream) {
  (void)in_sizes; (void)n_in; (void)out_size; (void)ws_size;

  const float* x = (const float*)d_in[0];
  const float* Wq = (const float*)d_in[1];
  const float* Wk = (const float*)d_in[2];
  const float* Wv = (const float*)d_in[3];
  const float* Wo = (const float*)d_in[4];
  const float* b_o = (const float*)d_in[5];
  const float* W1 = (const float*)d_in[6];
  const float* b1 = (const float*)d_in[7];
  const float* W2 = (const float*)d_in[8];
  const float* b2 = (const float*)d_in[9];
  const float* ln1g = (const float*)d_in[10];
  const float* ln1b = (const float*)d_in[11];
  const float* ln2g = (const float*)d_in[12];
  const float* ln2b = (const float*)d_in[13];

  char* ws = (char*)d_ws;
  __bf16* h = (__bf16*)(ws + 0);             // [4096][1024]  8 MB
  __bf16* W1T = (__bf16*)(ws + 8388608);     // [4096][1024]  8 MB
  __bf16* WqkvT = (__bf16*)(ws + 16777216);  // [3072][1024]  6 MB
  __bf16* WoT = (__bf16*)(ws + 23068672);    // [1024][1024]  2 MB
  __bf16* QKV = (__bf16*)(ws + 25165824);    // [4096][3072] 24 MB (V third unused)
  __bf16* VT = (__bf16*)(ws + 50331648);     // [1024][4096]  8 MB
  __bf16* ctx = (__bf16*)(ws + 58720256);    // [4096][1024]  8 MB
  __bf16* f1 = (__bf16*)(ws + 33554432);     // [4096][4096] 32 MB (QKV/VT/ctx dead)
  float* x1 = (float*)(ws + 67108864);       // [4096][1024] 16 MB f32
  __bf16* W2T = (__bf16*)(ws + 83886080);    // [1024][4096]  8 MB

  const dim3 blk(256);
  const dim3 blk512(512);

  // weight transposes + LN1 fused (one launch)
  prep_kernel<<<dim3(4096), blk, 0, stream>>>(Wq, Wk, Wv, Wo, W1, W2, x, ln1g,
                                              ln1b, WqkvT, WoT, W1T, W2T, h);

  // QKV = h @ [Wq|Wk|Wv]; V tiles written as key-permuted V^T (EPI 3)
  gemm256<3><<<dim3(16, 12), blk512, 0, stream>>>(
      h, 1024, WqkvT, 1024, (void*)QKV, 3072, 1024, nullptr, VT);

  // 512 blocks, XCD-pinned decode inside the kernel
  attn_kernel<<<dim3(512), blk, 0, stream>>>(QKV, VT, ctx);

  // x1 = x + ctx@Wo + b_o  (fused epilogue)  grid (m=64, n=8)
  gemm_bt<1, 64><<<dim3(64, 8), blk, 0, stream>>>(
      ctx, 1024, WoT, 1024, (void*)x1, 1024, 1024, b_o, x, 1024);

  // LN2 -> h  AND  d_out = x1 + b2
  ln2init_kernel<<<dim3(1024), blk, 0, stream>>>(x1, ln2g, ln2b, b2, h,
                                                 (float*)d_out);

  // f1 = relu(h2 @ W1 + b1)   grid (m=16, n=16), 256^2 tiles
  gemm256<2><<<dim3(16, 16), blk512, 0, stream>>>(
      h, 1024, W1T, 1024, (void*)f1, 4096, 1024, b1, nullptr);

  // f1@W2: split4 (Kb=1024), grid (m=16, n=4, z=4), f32 atomic add into d_out
  gemm256<4, 4><<<dim3(16, 4, 4), blk512, 0, stream>>>(
      f1, 4096, W2T, 4096, (void*)d_out, 1024, 1024, nullptr, nullptr);
}

// Round 12
// 295.442 us; speedup vs baseline: 1.0982x; 1.0982x over previous
//
#include <hip/hip_runtime.h>
#include <cstdint>
#include <cstddef>

// ---------------------------------------------------------------------------
// EncoderBlock: pre-norm transformer block, f32 I/O, bf16 MFMA internals.
//   prep(T(weights)+LN1) -> GEMM256(QKV, V written as key-permuted V^T in
//   epilogue) -> flash-attn(S^T, XCD-pinned) -> GEMM(Wo,+b_o+x -> x1 f32) ->
//   LN2 -> GEMM256(W1,+b,relu) -> GEMM256(W2,split4 -> bf16 partials) ->
//   reduce4(+b2,+x1) -> d_out                          [8 launches]
// ROUND-12: revert of round-11's atomic split-K (80us dispatch: 4-way
// same-address atomic RMW contention + doubled traffic). This restores the
// measured-best 299.5us configuration (round-9 GEMMs + round-10 attn).
// Big GEMMs: 256x256, BK=64, minimal-barrier schedule (2 barriers/K-tile,
// counted vmcnt(4)). Attention: ones-column-MFMA denominator, within-tile
// QK(kb+1) || exp(kb)+PV(kb) pipeline, XCD-pinned, epilogue-produced V^T.
// ---------------------------------------------------------------------------

typedef __attribute__((ext_vector_type(8))) __bf16 bf16x8;
typedef __attribute__((ext_vector_type(4))) __bf16 bf16x4;
typedef __attribute__((ext_vector_type(4))) float f32x4;

__device__ __forceinline__ void async16(const void* g, void* l) {
  __builtin_amdgcn_global_load_lds(
      (__attribute__((address_space(1))) void*)g,
      (__attribute__((address_space(3))) void*)l, 16, 0, 0);
}

__device__ __forceinline__ f32x4 mfma16(bf16x8 a, bf16x8 b, f32x4 c) {
  return __builtin_amdgcn_mfma_f32_16x16x32_bf16(a, b, c, 0, 0, 0);
}

template <int N>
__device__ __forceinline__ void wait_vmcnt() {
  if constexpr (N == 0) {
    asm volatile("s_waitcnt vmcnt(0)" ::: "memory");
  } else if constexpr (N == 3) {
    asm volatile("s_waitcnt vmcnt(3)" ::: "memory");
  } else {
    asm volatile("s_waitcnt vmcnt(4)" ::: "memory");
  }
}
__device__ __forceinline__ void barrier_raw() {
  asm volatile("s_barrier" ::: "memory");
}

// ---------------------------------------------------------------------------
// LayerNorm body (1 wave per token, D=1024). Shared by prep (LN1) and ln2.
// ---------------------------------------------------------------------------
__device__ __forceinline__ void ln_body(const float* __restrict__ xin,
                                        const float* __restrict__ g,
                                        const float* __restrict__ bt,
                                        __bf16* __restrict__ out, int tok,
                                        int lane) {
  const int base0 = lane * 8, base1 = 512 + lane * 8;
  const float* xr = xin + (size_t)tok * 1024;
  float v[16];
  float4 a0 = *(const float4*)(xr + base0);
  float4 a1 = *(const float4*)(xr + base0 + 4);
  float4 a2 = *(const float4*)(xr + base1);
  float4 a3 = *(const float4*)(xr + base1 + 4);
  v[0] = a0.x; v[1] = a0.y; v[2] = a0.z; v[3] = a0.w;
  v[4] = a1.x; v[5] = a1.y; v[6] = a1.z; v[7] = a1.w;
  v[8] = a2.x; v[9] = a2.y; v[10] = a2.z; v[11] = a2.w;
  v[12] = a3.x; v[13] = a3.y; v[14] = a3.z; v[15] = a3.w;
  float s = 0.f, s2 = 0.f;
#pragma unroll
  for (int i = 0; i < 16; i++) { s += v[i]; s2 += v[i] * v[i]; }
#pragma unroll
  for (int m = 1; m < 64; m <<= 1) {
    s += __shfl_xor(s, m);
    s2 += __shfl_xor(s2, m);
  }
  const float mean = s * (1.f / 1024.f);
  const float var = s2 * (1.f / 1024.f) - mean * mean;
  const float rstd = rsqrtf(var + 1e-6f);
  float4 g0 = *(const float4*)(g + base0), g1 = *(const float4*)(g + base0 + 4);
  float4 g2 = *(const float4*)(g + base1), g3 = *(const float4*)(g + base1 + 4);
  float4 b0 = *(const float4*)(bt + base0), b1v = *(const float4*)(bt + base0 + 4);
  float4 b2v = *(const float4*)(bt + base1), b3 = *(const float4*)(bt + base1 + 4);
  float gg[16] = {g0.x, g0.y, g0.z, g0.w, g1.x, g1.y, g1.z, g1.w,
                  g2.x, g2.y, g2.z, g2.w, g3.x, g3.y, g3.z, g3.w};
  float bb[16] = {b0.x, b0.y, b0.z, b0.w, b1v.x, b1v.y, b1v.z, b1v.w,
                  b2v.x, b2v.y, b2v.z, b2v.w, b3.x, b3.y, b3.z, b3.w};
  bf16x8 o0, o1;
#pragma unroll
  for (int j = 0; j < 8; j++) {
    o0[j] = (__bf16)((v[j] - mean) * rstd * gg[j] + bb[j]);
    o1[j] = (__bf16)((v[8 + j] - mean) * rstd * gg[8 + j] + bb[8 + j]);
  }
  __bf16* op = out + (size_t)tok * 1024;
  *(bf16x8*)(op + base0) = o0;
  *(bf16x8*)(op + base1) = o1;
}

// ---------------------------------------------------------------------------
// prep: ALL weight transposes (f32 -> bf16) + LN1, fused into one launch.
// ---------------------------------------------------------------------------
__global__ __launch_bounds__(256) void prep_kernel(
    const float* __restrict__ Wq, const float* __restrict__ Wk,
    const float* __restrict__ Wv, const float* __restrict__ Wo,
    const float* __restrict__ W1, const float* __restrict__ W2,
    const float* __restrict__ x, const float* __restrict__ ln1g,
    const float* __restrict__ ln1b, __bf16* __restrict__ WqkvT,
    __bf16* __restrict__ WoT, __bf16* __restrict__ W1T,
    __bf16* __restrict__ W2T, __bf16* __restrict__ h) {
  const int id = blockIdx.x;
  if (id >= 3072) {
    const int tok = (id - 3072) * 4 + (threadIdx.x >> 6);
    ln_body(x, ln1g, ln1b, h, tok, threadIdx.x & 63);
    return;
  }
  const float* in;
  __bf16* out;
  int ld_in, ld_out, c0, r0;
  if (id < 1024) {
    const int which = id >> 8, tl = id & 255;
    c0 = (tl & 15) * 64;
    r0 = (tl >> 4) * 64;
    ld_in = 1024;
    ld_out = 1024;
    if (which == 0) { in = Wq; out = WqkvT; }
    else if (which == 1) { in = Wk; out = WqkvT + 1048576; }
    else if (which == 2) { in = Wv; out = WqkvT + 2097152; }
    else { in = Wo; out = WoT; }
  } else if (id < 2048) {
    const int tl = id - 1024;
    c0 = (tl & 63) * 64;
    r0 = (tl >> 6) * 64;
    in = W1; out = W1T; ld_in = 4096; ld_out = 1024;
  } else {
    const int tl = id - 2048;
    c0 = (tl & 15) * 64;
    r0 = (tl >> 4) * 64;
    in = W2; out = W2T; ld_in = 1024; ld_out = 4096;
  }
  __shared__ __bf16 tile[64][65];
  const int tx = threadIdx.x & 63, ty = threadIdx.x >> 6;
#pragma unroll
  for (int i = 0; i < 16; i++) {
    int r = ty + i * 4;
    tile[r][tx] = (__bf16)in[(size_t)(r0 + r) * ld_in + c0 + tx];
  }
  __syncthreads();
#pragma unroll
  for (int i = 0; i < 16; i++) {
    int r = ty + i * 4;
    out[(size_t)(c0 + r) * ld_out + r0 + tx] = tile[tx][r];
  }
}

// ---------------------------------------------------------------------------
// LayerNorm standalone (LN2).
// ---------------------------------------------------------------------------
__global__ __launch_bounds__(256) void ln_kernel(
    const float* __restrict__ xin, const float* __restrict__ g,
    const float* __restrict__ bt, __bf16* __restrict__ out) {
  const int tok = blockIdx.x * 4 + (threadIdx.x >> 6);
  ln_body(xin, g, bt, out, tok, threadIdx.x & 63);
}

// ---------------------------------------------------------------------------
// gemm256: C[M,N] = A[M,K](bf16) * BT[N,K](bf16)^T. 256x256 tile, BK=64,
// 512 thr = 2x4 waves. Minimal-barrier K-loop (2 barriers/K-tile), counted
// vmcnt(4). setprio around MFMA clusters; chunk-XOR LDS swizzle.
// EPI: 0 -> bf16 (plain / split-K partial); 2 -> +bias(f32), relu -> bf16;
//      3 -> QKV: V tiles (n0>=2048) write key-permuted V^T directly.
// ---------------------------------------------------------------------------
template <int EPI, int SPLITS = 1>
__global__ __launch_bounds__(512, 2) void gemm256(
    const __bf16* __restrict__ A, int lda, const __bf16* __restrict__ BT,
    int ldb, void* __restrict__ C, int ldc, int Kb,
    const float* __restrict__ bias, __bf16* __restrict__ VTout) {
  const int t = threadIdx.x;
  const int m0 = blockIdx.x * 256, n0 = blockIdx.y * 256;
  const int kz = (SPLITS > 1) ? blockIdx.z : 0;
  __shared__ __align__(16) __bf16 As[2][2][8192];
  __shared__ __align__(16) __bf16 Bs[2][2][8192];
  const int lane = t & 63;
  const int quad = lane >> 4, l15 = lane & 15;
  const int w = t >> 6, wm = w >> 2, wn = w & 3;

  f32x4 acc[8][4] = {};

  const int rr = t >> 3;
  const int ca = (t & 7) ^ (rr & 7);
  const int cc = rr & 31;
  const int wnb = t >> 8;
  const int cb = (t & 7) ^ (cc & 7);
  const __bf16* gA = A + (size_t)kz * Kb + (size_t)(m0 + rr) * lda + ca * 8;
  const __bf16* gB = BT + (size_t)kz * Kb +
                     (size_t)(n0 + wnb * 64 + cc) * ldb + cb * 8;
  const size_t a64 = (size_t)64 * lda, a128 = (size_t)128 * lda;
  const size_t b32 = (size_t)32 * ldb, b128 = (size_t)128 * ldb;

  auto stageA = [&](int buf, int mq, int ko) {
    const __bf16* g = gA + (mq ? a64 : 0) + ko;
    __bf16* l = &As[buf][mq][t * 8];
    async16(g, l);
    async16(g + a128, l + 4096);
  };
  auto stageB = [&](int buf, int nq, int ko) {
    const __bf16* g = gB + (nq ? b32 : 0) + ko;
    __bf16* l = &Bs[buf][nq][t * 8];
    async16(g, l);
    async16(g + b128, l + 4096);
  };

  const int arow = wm * 4096 + l15 * 64;
  const int brow = wn * 2048 + l15 * 64;
  const int x7 = l15 & 7;

  auto loadA = [&](int buf, int mq, bf16x8 (&af)[4][2]) {
#pragma unroll
    for (int mi = 0; mi < 4; mi++)
#pragma unroll
      for (int kk = 0; kk < 2; kk++)
        af[mi][kk] = *(const bf16x8*)&As[buf][mq]
            [arow + mi * 1024 + (((kk * 4 + quad) ^ x7) * 8)];
  };
  auto loadB = [&](int buf, int nq, bf16x8 (&bv)[2][2]) {
#pragma unroll
    for (int ni = 0; ni < 2; ni++)
#pragma unroll
      for (int kk = 0; kk < 2; kk++)
        bv[ni][kk] = *(const bf16x8*)&Bs[buf][nq]
            [brow + ni * 1024 + (((kk * 4 + quad) ^ x7) * 8)];
  };
  auto mm = [&](int mq, int nq, const bf16x8 (&af)[4][2],
                const bf16x8 (&bv)[2][2]) {
    __builtin_amdgcn_s_setprio(1);
#pragma unroll
    for (int mi = 0; mi < 4; mi++)
#pragma unroll
      for (int ni = 0; ni < 2; ni++)
#pragma unroll
        for (int kk = 0; kk < 2; kk++)
          acc[mq * 4 + mi][nq * 2 + ni] =
              mfma16(af[mi][kk], bv[ni][kk], acc[mq * 4 + mi][nq * 2 + ni]);
    __builtin_amdgcn_s_setprio(0);
  };

  const int NT = Kb / 64;
  stageA(0, 0, 0); stageB(0, 0, 0); stageA(0, 1, 0); stageB(0, 1, 0);
  stageA(1, 0, 64); stageB(1, 0, 64);
  wait_vmcnt<4>();
  barrier_raw();

  bf16x8 af[4][2], b0[2][2], b1[2][2];
  for (int s = 0; s < NT; ++s) {
    const int buf = s & 1;
    const int ko1 = (s + 1) * 64, ko2 = (s + 2) * 64;
    loadA(buf, 0, af);
    loadB(buf, 0, b0);
    loadB(buf, 1, b1);
    if (s + 1 < NT) {
      stageA(buf ^ 1, 1, ko1);
      stageB(buf ^ 1, 1, ko1);
    }
    mm(0, 0, af, b0);
    mm(0, 1, af, b1);
    barrier_raw();  // all waves' A0/B0/B1 reads done before ko2 overwrites
    loadA(buf, 1, af);
    if (s + 2 < NT) {
      stageA(buf, 0, ko2);
      stageB(buf, 0, ko2);
      wait_vmcnt<4>();  // drains ko1 (tile s+1 A1,B1) + older; leaves ko2
    } else {
      wait_vmcnt<0>();
    }
    mm(1, 0, af, b0);
    mm(1, 1, af, b1);
    barrier_raw();  // A1/B1 reads done before next iter's ko1 overwrites
  }

  if constexpr (EPI == 3) {
    if (n0 >= 2048) {
      // V tile -> key-permuted V^T (feature-major, token permuted within 32)
      const int colb = m0 + wm * 128;
#pragma unroll
      for (int mi = 0; mi < 8; mi++) {
        const int tcol = colb + (mi >> 1) * 32 + quad * 8 + (mi & 1) * 4;
#pragma unroll
        for (int ni = 0; ni < 4; ni++) {
          const int vrow = n0 - 2048 + wn * 64 + ni * 16 + l15;
          bf16x4 o;
#pragma unroll
          for (int r = 0; r < 4; r++) o[r] = (__bf16)acc[mi][ni][r];
          *(bf16x4*)&VTout[(size_t)vrow * 4096 + tcol] = o;
        }
      }
      return;
    }
  }

  float biasv[4];
  if constexpr (EPI == 2) {
#pragma unroll
    for (int ni = 0; ni < 4; ni++)
      biasv[ni] = bias[n0 + wn * 64 + ni * 16 + l15];
  }
  __bf16* Cb = (__bf16*)C;
  if constexpr (SPLITS > 1)
    Cb += (size_t)kz * (size_t)gridDim.x * 256 * ldc;
#pragma unroll
  for (int mi = 0; mi < 8; mi++)
#pragma unroll
    for (int ni = 0; ni < 4; ni++)
#pragma unroll
      for (int r = 0; r < 4; r++) {
        const int row = m0 + wm * 128 + mi * 16 + quad * 4 + r;
        const int col = n0 + wn * 64 + ni * 16 + l15;
        float v = acc[mi][ni][r];
        if constexpr (EPI == 0 || EPI == 3) {
          Cb[(size_t)row * ldc + col] = (__bf16)v;
        } else {
          v += biasv[ni];
          Cb[(size_t)row * ldc + col] = (__bf16)fmaxf(v, 0.f);
        }
      }
}

// ---------------------------------------------------------------------------
// Older 128-wide GEMM (kept for Wo). EPI == 1: +bias(f32)+res(f32) -> f32.
// ---------------------------------------------------------------------------
template <int EPI, int TM, int SPLITS = 1>
__global__ __launch_bounds__(256) void gemm_bt(
    const __bf16* __restrict__ A, int lda, const __bf16* __restrict__ BT,
    int ldb, void* __restrict__ C, int ldc, int Kb,
    const float* __restrict__ bias, const float* __restrict__ res, int ldres) {
  const int t = threadIdx.x;
  const int m0 = blockIdx.x * TM, n0 = blockIdx.y * 128;
  const int kz = (SPLITS > 1) ? blockIdx.z : 0;
  __shared__ __align__(16) __bf16 As[3][TM * 32];
  __shared__ __align__(16) __bf16 Bs[3][128 * 32];
  const int lane = t & 63, w = t >> 6;
  const int quad = lane >> 4, l15 = lane & 15;
  const int wm = w >> 1, wn = w & 1;
  constexpr int MF = TM / 32;
  constexpr int LOADS = TM / 64 + 2;

  f32x4 acc[MF][4] = {};

  const int swc = ((t & 3) ^ ((t >> 3) & 3)) * 8;
  const __bf16* ga = A + (size_t)(m0 + (t >> 2)) * lda + swc + (size_t)kz * Kb;
  const __bf16* gb = BT + (size_t)(n0 + (t >> 2)) * ldb + swc + (size_t)kz * Kb;
  const size_t a64 = (size_t)64 * lda, b64 = (size_t)64 * ldb;

  auto stage = [&](int buf) {
#pragma unroll
    for (int i = 0; i < TM / 64; i++)
      async16(ga + i * a64, As[buf] + t * 8 + i * 2048);
    async16(gb, Bs[buf] + t * 8);
    async16(gb + b64, Bs[buf] + t * 8 + 2048);
    ga += 32;
    gb += 32;
  };
  const int ce = (quad ^ ((l15 >> 1) & 3)) * 8;
  auto compute = [&](int buf) {
    bf16x8 af[MF], bfr[4];
#pragma unroll
    for (int i = 0; i < MF; i++)
      af[i] = *(const bf16x8*)&As[buf][(wm * (TM / 2) + i * 16 + l15) * 32 + ce];
#pragma unroll
    for (int i = 0; i < 4; i++)
      bfr[i] = *(const bf16x8*)&Bs[buf][(wn * 64 + i * 16 + l15) * 32 + ce];
#pragma unroll
    for (int mi = 0; mi < MF; mi++)
#pragma unroll
      for (int ni = 0; ni < 4; ni++)
        acc[mi][ni] = mfma16(af[mi], bfr[ni], acc[mi][ni]);
  };

  const int iters = Kb / 32;
  stage(0);
  stage(1);
  int cur = 0, stg = 2;
  for (int it = 0; it < iters - 1; ++it) {
    wait_vmcnt<LOADS>();
    barrier_raw();
    if (it + 2 < iters) stage(stg);
    compute(cur);
    cur = (cur == 2) ? 0 : cur + 1;
    stg = (stg == 2) ? 0 : stg + 1;
  }
  wait_vmcnt<0>();
  barrier_raw();
  compute(cur);

  float biasv[4];
  if constexpr (EPI != 0) {
#pragma unroll
    for (int ni = 0; ni < 4; ni++)
      biasv[ni] = bias[n0 + wn * 64 + ni * 16 + l15];
  }
  __bf16* Cb = (__bf16*)C;
  if constexpr (SPLITS > 1)
    Cb += (size_t)kz * gridDim.x * TM * ldc;
#pragma unroll
  for (int mi = 0; mi < MF; mi++)
#pragma unroll
    for (int ni = 0; ni < 4; ni++)
#pragma unroll
      for (int r = 0; r < 4; r++) {
        const int row = m0 + wm * (TM / 2) + mi * 16 + quad * 4 + r;
        const int col = n0 + wn * 64 + ni * 16 + l15;
        float v = acc[mi][ni][r];
        if constexpr (EPI == 0) {
          Cb[(size_t)row * ldc + col] = (__bf16)v;
        } else if constexpr (EPI == 1) {
          v += biasv[ni] + res[(size_t)row * ldres + col];
          ((float*)C)[(size_t)row * ldc + col] = v;
        } else {
          v += biasv[ni];
          ((__bf16*)C)[(size_t)row * ldc + col] = (__bf16)fmaxf(v, 0.f);
        }
      }
}

// ---------------------------------------------------------------------------
// Split-K(4) reduce: out = P0+P1+P2+P3 + bias[col] + res (f32).
// ---------------------------------------------------------------------------
__global__ __launch_bounds__(256) void reduce_split4(
    const __bf16* __restrict__ P, const float* __restrict__ bias,
    const float* __restrict__ res, float* __restrict__ out) {
  const int row = blockIdx.x, c = threadIdx.x * 4;
  const size_t i = (size_t)row * 1024 + c;
  float4 r = *(const float4*)(res + i);
  float4 bv = *(const float4*)(bias + c);
  float s0 = r.x + bv.x, s1 = r.y + bv.y, s2 = r.z + bv.z, s3 = r.w + bv.w;
#pragma unroll
  for (int j = 0; j < 4; j++) {
    bf16x4 p = *(const bf16x4*)(P + (size_t)j * 4194304 + i);
    s0 += (float)p[0];
    s1 += (float)p[1];
    s2 += (float)p[2];
    s3 += (float)p[3];
  }
  float4 o = {s0, s1, s2, s3};
  *(float4*)(out + i) = o;
}

// ---------------------------------------------------------------------------
// Flash attention via S^T (round-10 config). QBLK=128 (4 waves x 32 q as 2
// q-groups), KVBLK=128, XCD-pinned grid 512; K LDS 2x16KB; V^T LDS 2x16KB
// [64][128]; quad-grouped key-permuted V^T from the QKV-gemm epilogue;
// ones-column MFMA denominator; within-tile QK(kb+1) || exp(kb)+PV(kb).
// ---------------------------------------------------------------------------
__global__ __launch_bounds__(256, 2) void attn_kernel(
    const __bf16* __restrict__ QKV, const __bf16* __restrict__ VT,
    __bf16* __restrict__ ctx) {
  const int id = blockIdx.x;
  const int xg = id & 7, idx = id >> 3;  // 512 blocks
  const int bh = xg * 4 + (idx & 3);     // head-group pinned to XCD
  const int qt = idx >> 2;               // 0..15
  const int b = bh >> 4, h = bh & 15;
  const int t = threadIdx.x, w = t >> 6, lane = t & 63;
  const int quad = lane >> 4, l15 = lane & 15;
  const int tok0 = b * 2048;
  const int q0w = tok0 + qt * 128 + w * 32;

  __shared__ __align__(16) __bf16 Ks[2][128 * 64];   // [key][d]
  __shared__ __align__(16) __bf16 VTs[2][64 * 128];  // [d][key-perm]

  const float qs = 0.18033688011112042f;  // log2(e)/8 -> exp2-domain softmax
  bf16x8 qf[2][2];
#pragma unroll
  for (int mi = 0; mi < 2; mi++)
#pragma unroll
    for (int kb = 0; kb < 2; kb++) {
      const __bf16* src = QKV + (size_t)(q0w + mi * 16 + l15) * 3072 + h * 64 +
                          kb * 32 + quad * 8;
      bf16x8 r = *(const bf16x8*)src;
#pragma unroll
      for (int j = 0; j < 8; j++) r[j] = (__bf16)((float)r[j] * qs);
      qf[mi][kb] = r;
    }

  bf16x8 onesv;
#pragma unroll
  for (int j = 0; j < 8; j++) onesv[j] = (__bf16)1.0f;

  f32x4 O[2][4] = {};
  f32x4 Ol[2] = {};  // ones-column accumulation: softmax denominator per q-row

  const int krow = t >> 3;                       // 0..31 (K staging)
  const int kcg = (((t & 7) ^ (krow & 7)) * 8);  // K source chunk
  const int vrow = t >> 4;                       // 0..15 (V staging)
  const int vcg = (((t & 15) ^ (vrow & 7)) * 8); // V source chunk (16/row)
  const int x7 = l15 & 7;

  auto stage = [&](int buf, int kt) {
    const int ktok = tok0 + kt * 128;
#pragma unroll
    for (int j = 0; j < 4; j++) {
      const __bf16* gp =
          QKV + (size_t)(ktok + krow + j * 32) * 3072 + 1024 + h * 64 + kcg;
      async16(gp, Ks[buf] + t * 8 + j * 2048);
    }
#pragma unroll
    for (int j = 0; j < 4; j++) {
      const __bf16* gp =
          VT + (size_t)(h * 64 + vrow + j * 16) * 4096 + ktok + vcg;
      async16(gp, VTs[buf] + t * 8 + j * 2048);
    }
  };

  stage(0, 0);
  wait_vmcnt<0>();
  barrier_raw();

  int buf = 0;
  for (int kt = 0; kt < 16; ++kt) {
    if (kt + 1 < 16) stage(buf ^ 1, kt + 1);  // prefetch next K/V tile

    f32x4 sT[2][8];
    auto qkblk = [&](int kb) {
      __builtin_amdgcn_s_setprio(1);
#pragma unroll
      for (int kt8 = 2 * kb; kt8 < 2 * kb + 2; kt8++) {
        f32x4 a0 = {}, a1 = {};
#pragma unroll
        for (int kq = 0; kq < 2; kq++) {
          bf16x8 kf = *(const bf16x8*)&Ks[buf][(kt8 * 16 + l15) * 64 +
                                              (((kq * 4 + quad) ^ x7) * 8)];
          a0 = mfma16(kf, qf[0][kq], a0);
          a1 = mfma16(kf, qf[1][kq], a1);
        }
        sT[0][kt8] = a0;
        sT[1][kt8] = a1;
      }
      __builtin_amdgcn_s_setprio(0);
    };

    qkblk(0);
#pragma unroll
    for (int kb = 0; kb < 4; kb++) {
      if (kb < 3) qkblk(kb + 1);
      bf16x8 pf0, pf1;
#pragma unroll
      for (int hf = 0; hf < 2; hf++)
#pragma unroll
        for (int r = 0; r < 4; r++) {
          const float p0 = __builtin_amdgcn_exp2f(sT[0][2 * kb + hf][r]);
          const float p1 = __builtin_amdgcn_exp2f(sT[1][2 * kb + hf][r]);
          pf0[hf * 4 + r] = (__bf16)p0;
          pf1[hf * 4 + r] = (__bf16)p1;
        }
      __builtin_amdgcn_s_setprio(1);
#pragma unroll
      for (int nd = 0; nd < 4; nd++) {
        bf16x8 vf = *(const bf16x8*)&VTs[buf][(nd * 16 + l15) * 128 +
                                             (((4 * kb + quad) ^ x7) * 8)];
        O[0][nd] = mfma16(pf0, vf, O[0][nd]);
        O[1][nd] = mfma16(pf1, vf, O[1][nd]);
      }
      Ol[0] = mfma16(pf0, onesv, Ol[0]);
      Ol[1] = mfma16(pf1, onesv, Ol[1]);
      __builtin_amdgcn_s_setprio(0);
    }

    wait_vmcnt<0>();  // drain prefetch (issued before compute; L2-hit ~free)
    barrier_raw();    // all waves done reading buf; buf^1 fully staged
    buf ^= 1;
  }

  // epilogue: normalize by Ol (same row mapping as O), store (per q-group)
#pragma unroll
  for (int mi = 0; mi < 2; mi++) {
    float rl[4];
#pragma unroll
    for (int r = 0; r < 4; r++) rl[r] = 1.0f / Ol[mi][r];
#pragma unroll
    for (int nd = 0; nd < 4; nd++)
#pragma unroll
      for (int r = 0; r < 4; r++) {
        const int tokq = q0w + mi * 16 + quad * 4 + r;
        const int col = h * 64 + nd * 16 + l15;
        ctx[(size_t)tokq * 1024 + col] = (__bf16)(O[mi][nd][r] * rl[r]);
      }
  }
}

// ---------------------------------------------------------------------------
// Workspace layout (88 MB peak), lifetime-packed:
//   [ 0, 8)  h      [ 8,16) W1T   [16,22) WqkvT   [22,24) WoT
//   [24,48)  QKV    [48,56) VT    [56,64) ctx
//   [32,64)  f1 (after attn: QKV tail/VT/ctx dead)
//   [ 0,32)  Pw2 (4 split-K partials; early bufs dead by then)
//   [64,80)  x1 (f32)             [80,88) W2T
// ---------------------------------------------------------------------------
extern "C" void kernel_launch(void* const* d_in, const int* in_sizes, int n_in,
                              void* d_out, int out_size, void* d_ws,
                              size_t ws_size, hipStream_t stream) {
  (void)in_sizes; (void)n_in; (void)out_size; (void)ws_size;

  const float* x = (const float*)d_in[0];
  const float* Wq = (const float*)d_in[1];
  const float* Wk = (const float*)d_in[2];
  const float* Wv = (const float*)d_in[3];
  const float* Wo = (const float*)d_in[4];
  const float* b_o = (const float*)d_in[5];
  const float* W1 = (const float*)d_in[6];
  const float* b1 = (const float*)d_in[7];
  const float* W2 = (const float*)d_in[8];
  const float* b2 = (const float*)d_in[9];
  const float* ln1g = (const float*)d_in[10];
  const float* ln1b = (const float*)d_in[11];
  const float* ln2g = (const float*)d_in[12];
  const float* ln2b = (const float*)d_in[13];

  char* ws = (char*)d_ws;
  __bf16* h = (__bf16*)(ws + 0);             // [4096][1024]  8 MB
  __bf16* W1T = (__bf16*)(ws + 8388608);     // [4096][1024]  8 MB
  __bf16* WqkvT = (__bf16*)(ws + 16777216);  // [3072][1024]  6 MB
  __bf16* WoT = (__bf16*)(ws + 23068672);    // [1024][1024]  2 MB
  __bf16* QKV = (__bf16*)(ws + 25165824);    // [4096][3072] 24 MB (V third unused)
  __bf16* VT = (__bf16*)(ws + 50331648);     // [1024][4096]  8 MB
  __bf16* ctx = (__bf16*)(ws + 58720256);    // [4096][1024]  8 MB
  __bf16* f1 = (__bf16*)(ws + 33554432);     // [4096][4096] 32 MB (QKV/VT/ctx dead)
  __bf16* Pw2 = (__bf16*)(ws + 0);           // 4x[4096][1024] 32 MB (early bufs dead)
  float* x1 = (float*)(ws + 67108864);       // [4096][1024] 16 MB f32
  __bf16* W2T = (__bf16*)(ws + 83886080);    // [1024][4096]  8 MB

  const dim3 blk(256);
  const dim3 blk512(512);

  // weight transposes + LN1 fused (one launch)
  prep_kernel<<<dim3(4096), blk, 0, stream>>>(Wq, Wk, Wv, Wo, W1, W2, x, ln1g,
                                              ln1b, WqkvT, WoT, W1T, W2T, h);

  // QKV = h @ [Wq|Wk|Wv]; V tiles written as key-permuted V^T (EPI 3)
  gemm256<3><<<dim3(16, 12), blk512, 0, stream>>>(
      h, 1024, WqkvT, 1024, (void*)QKV, 3072, 1024, nullptr, VT);

  // 512 blocks, XCD-pinned decode inside the kernel
  attn_kernel<<<dim3(512), blk, 0, stream>>>(QKV, VT, ctx);

  // x1 = x + ctx@Wo + b_o  (fused epilogue)  grid (m=64, n=8)
  gemm_bt<1, 64><<<dim3(64, 8), blk, 0, stream>>>(
      ctx, 1024, WoT, 1024, (void*)x1, 1024, 1024, b_o, x, 1024);

  ln_kernel<<<dim3(1024), blk, 0, stream>>>(x1, ln2g, ln2b, h);

  // f1 = relu(h2 @ W1 + b1)   grid (m=16, n=16), 256^2 tiles
  gemm256<2><<<dim3(16, 16), blk512, 0, stream>>>(
      h, 1024, W1T, 1024, (void*)f1, 4096, 1024, b1, nullptr);

  // f1@W2: split4 (Kb=1024), grid (m=16, n=4, z=4) -> bf16 partials
  gemm256<0, 4><<<dim3(16, 4, 4), blk512, 0, stream>>>(
      f1, 4096, W2T, 4096, (void*)Pw2, 1024, 1024, nullptr, nullptr);
  // d_out = P0+P1+P2+P3 + b2 + x1
  reduce_split4<<<dim3(4096), blk, 0, stream>>>(Pw2, b2, x1, (float*)d_out);
}